// Round 1
// baseline (2108.023 us; speedup 1.0000x reference)
//
#include <hip/hip_runtime.h>
#include <hip/hip_bf16.h>

// LightGCN on MI355X.
// Strategy: per-call CSR build (counting sort), gather-SpMM (one wave per row,
// lane = embedding dim), layer-2 fused into the batch epilogue (only 16K rows
// needed). No float atomics.

#define DIM 64

// ---------------- CSR build ----------------

__global__ void hist_kernel(const int* __restrict__ rows, int* __restrict__ deg,
                            int n_edges) {
    int e = blockIdx.x * blockDim.x + threadIdx.x;
    if (e < n_edges) atomicAdd(&deg[rows[e]], 1);
}

// Single-block exclusive scan over n (~300k) degrees -> offs[0..n], cursor copy.
__global__ void scan_kernel(const int* __restrict__ deg, int* __restrict__ offs,
                            int* __restrict__ cursor, int n) {
    __shared__ int ssum[1024];
    __shared__ int sbase[1024];
    int t = threadIdx.x;
    int chunk = (n + 1023) / 1024;
    int lo = t * chunk;
    int hi = lo + chunk; if (hi > n) hi = n; if (lo > n) lo = n;
    int s = 0;
    for (int i = lo; i < hi; ++i) s += deg[i];
    ssum[t] = s;
    __syncthreads();
    if (t == 0) {
        int run = 0;
        for (int i = 0; i < 1024; ++i) { sbase[i] = run; run += ssum[i]; }
        offs[n] = run;
    }
    __syncthreads();
    int run = sbase[t];
    for (int i = lo; i < hi; ++i) {
        offs[i] = run;
        cursor[i] = run;
        run += deg[i];
    }
}

__global__ void scatter_kernel(const int* __restrict__ rows,
                               const int* __restrict__ cols,
                               const float* __restrict__ vals,
                               int* __restrict__ cursor,
                               int* __restrict__ csr_col,
                               float* __restrict__ csr_val,
                               int n_edges) {
    int e = blockIdx.x * blockDim.x + threadIdx.x;
    if (e >= n_edges) return;
    int r = rows[e];
    int pos = atomicAdd(&cursor[r], 1);
    csr_col[pos] = cols[e];
    csr_val[pos] = vals[e];
}

// ---------------- Layer 1: full SpMM (gather form) ----------------
// One wave per output row; lane l accumulates dim l. Each edge -> one
// coalesced 256B read of the source embedding row.
__global__ void spmm_layer1(const int* __restrict__ offs,
                            const int* __restrict__ csr_col,
                            const float* __restrict__ csr_val,
                            const float* __restrict__ user_emb,
                            const float* __restrict__ item_emb,
                            float* __restrict__ emb1,
                            int n_nodes, int n_users) {
    int wave = (blockIdx.x * blockDim.x + threadIdx.x) >> 6;
    int lane = threadIdx.x & 63;
    if (wave >= n_nodes) return;
    int start = offs[wave];
    int end   = offs[wave + 1];
    float acc = 0.0f;
    for (int e = start; e < end; ++e) {
        int c = csr_col[e];
        float v = csr_val[e];
        const float* src = (c < n_users) ? (user_emb + (size_t)c * DIM)
                                         : (item_emb + (size_t)(c - n_users) * DIM);
        acc += v * src[lane];
    }
    emb1[(size_t)wave * DIM + lane] = acc;
}

// ---------------- Layer 2 (batch rows only) + epilogue ----------------
// One wave per batch element: compute emb2 at the user node and item node,
// form light_out = (emb0+emb1+emb2)/3, write both embeddings and the dot.
__global__ void epilogue_kernel(const int* __restrict__ users,
                                const int* __restrict__ items,
                                const float* __restrict__ user_emb,
                                const float* __restrict__ item_emb,
                                const float* __restrict__ emb1,
                                const int* __restrict__ offs,
                                const int* __restrict__ csr_col,
                                const float* __restrict__ csr_val,
                                float* __restrict__ out_u,
                                float* __restrict__ out_i,
                                float* __restrict__ out_s,
                                int batch, int n_users) {
    int wave = (blockIdx.x * blockDim.x + threadIdx.x) >> 6;
    int lane = threadIdx.x & 63;
    if (wave >= batch) return;
    int u  = users[wave];
    int it = items[wave];
    int ni = n_users + it;

    float ue2 = 0.0f;
    for (int e = offs[u]; e < offs[u + 1]; ++e)
        ue2 += csr_val[e] * emb1[(size_t)csr_col[e] * DIM + lane];
    float ie2 = 0.0f;
    for (int e = offs[ni]; e < offs[ni + 1]; ++e)
        ie2 += csr_val[e] * emb1[(size_t)csr_col[e] * DIM + lane];

    const float inv3 = 1.0f / 3.0f;
    float ue = (user_emb[(size_t)u * DIM + lane] + emb1[(size_t)u * DIM + lane] + ue2) * inv3;
    float ie = (item_emb[(size_t)it * DIM + lane] + emb1[(size_t)ni * DIM + lane] + ie2) * inv3;

    out_u[(size_t)wave * DIM + lane] = ue;
    out_i[(size_t)wave * DIM + lane] = ie;

    float s = ue * ie;
    #pragma unroll
    for (int o = 32; o > 0; o >>= 1) s += __shfl_down(s, o);
    if (lane == 0) out_s[wave] = s;
}

extern "C" void kernel_launch(void* const* d_in, const int* in_sizes, int n_in,
                              void* d_out, int out_size, void* d_ws, size_t ws_size,
                              hipStream_t stream) {
    const int*   users    = (const int*)d_in[0];
    const int*   items    = (const int*)d_in[1];
    const float* user_emb = (const float*)d_in[2];
    const float* item_emb = (const float*)d_in[3];
    const int*   rows     = (const int*)d_in[4];
    const int*   cols     = (const int*)d_in[5];
    const float* vals     = (const float*)d_in[6];

    const int batch   = in_sizes[0];
    const int n_users = in_sizes[2] / DIM;
    const int n_items = in_sizes[3] / DIM;
    const int n_nodes = n_users + n_items;
    const int n_edges = in_sizes[4];

    // Workspace layout
    char* p = (char*)d_ws;
    float* emb1   = (float*)p;  p += (size_t)n_nodes * DIM * sizeof(float);
    int*   deg    = (int*)p;    p += (size_t)n_nodes * sizeof(int);
    int*   offs   = (int*)p;    p += (size_t)(n_nodes + 1) * sizeof(int);
    int*   cursor = (int*)p;    p += (size_t)n_nodes * sizeof(int);
    int*   csr_col = (int*)p;   p += (size_t)n_edges * sizeof(int);
    float* csr_val = (float*)p; p += (size_t)n_edges * sizeof(float);

    float* out_u = (float*)d_out;
    float* out_i = out_u + (size_t)batch * DIM;
    float* out_s = out_i + (size_t)batch * DIM;

    // 1. CSR build
    hipMemsetAsync(deg, 0, (size_t)n_nodes * sizeof(int), stream);
    {
        int blocks = (n_edges + 255) / 256;
        hist_kernel<<<blocks, 256, 0, stream>>>(rows, deg, n_edges);
    }
    scan_kernel<<<1, 1024, 0, stream>>>(deg, offs, cursor, n_nodes);
    {
        int blocks = (n_edges + 255) / 256;
        scatter_kernel<<<blocks, 256, 0, stream>>>(rows, cols, vals, cursor,
                                                   csr_col, csr_val, n_edges);
    }

    // 2. Layer 1 full SpMM: emb1 = A @ emb0
    {
        int waves_per_block = 4;  // 256 threads
        int blocks = (n_nodes + waves_per_block - 1) / waves_per_block;
        spmm_layer1<<<blocks, 256, 0, stream>>>(offs, csr_col, csr_val,
                                                user_emb, item_emb, emb1,
                                                n_nodes, n_users);
    }

    // 3. Layer 2 (batch rows only) + outputs
    {
        int waves_per_block = 4;
        int blocks = (batch + waves_per_block - 1) / waves_per_block;
        epilogue_kernel<<<blocks, 256, 0, stream>>>(users, items,
                                                    user_emb, item_emb, emb1,
                                                    offs, csr_col, csr_val,
                                                    out_u, out_i, out_s,
                                                    batch, n_users);
    }
}

// Round 2
// 1361.566 us; speedup vs baseline: 1.5482x; 1.5482x over previous
//
#include <hip/hip_runtime.h>
#include <hip/hip_bf16.h>

// LightGCN on MI355X.
// R1: replace 684us single-block scan with 3-kernel multi-block scan;
// pack CSR (col,val) as int2 to halve scattered write transactions.

#define DIM 64
#define SCAN_ITEMS 2048   // elements per block in the scan (256 thr x 8)

// ---------------- CSR build ----------------

__global__ void hist_kernel(const int* __restrict__ rows, int* __restrict__ deg,
                            int n_edges) {
    int e = blockIdx.x * blockDim.x + threadIdx.x;
    if (e < n_edges) atomicAdd(&deg[rows[e]], 1);
}

// Pass 1: per-block sums of deg.
__global__ void scan_blocksums(const int* __restrict__ deg,
                               int* __restrict__ bsums, int n) {
    int base = blockIdx.x * SCAN_ITEMS;
    int s = 0;
    #pragma unroll
    for (int k = 0; k < 8; ++k) {
        int i = base + k * 256 + threadIdx.x;
        if (i < n) s += deg[i];
    }
    #pragma unroll
    for (int o = 32; o > 0; o >>= 1) s += __shfl_down(s, o);
    __shared__ int ws[4];
    int wave = threadIdx.x >> 6, lane = threadIdx.x & 63;
    if (lane == 0) ws[wave] = s;
    __syncthreads();
    if (threadIdx.x == 0) bsums[blockIdx.x] = ws[0] + ws[1] + ws[2] + ws[3];
}

// Pass 2: exclusive scan of block sums (nb small, single block, LDS-serial).
__global__ void scan_bases(const int* __restrict__ bsums, int* __restrict__ bbase,
                           int* __restrict__ offs, int n, int nb) {
    __shared__ int s[2048];
    int t = threadIdx.x;
    for (int i = t; i < nb; i += blockDim.x) s[i] = bsums[i];
    __syncthreads();
    if (t == 0) {
        int run = 0;
        for (int i = 0; i < nb; ++i) { int v = s[i]; s[i] = run; run += v; }
        offs[n] = run;   // total edge count
    }
    __syncthreads();
    for (int i = t; i < nb; i += blockDim.x) bbase[i] = s[i];
}

// Pass 3: per-block exclusive scan + base, writes offs and cursor.
__global__ void scan_final(const int* __restrict__ deg,
                           const int* __restrict__ bbase,
                           int* __restrict__ offs, int* __restrict__ cursor,
                           int n) {
    int base = blockIdx.x * SCAN_ITEMS;
    int t = threadIdx.x;
    int lane = t & 63, wave = t >> 6;
    int i0 = base + t * 8;

    int v[8];
    bool fast = (base + SCAN_ITEMS) <= n;
    if (fast) {
        int4 a = *(const int4*)(deg + i0);
        int4 b = *(const int4*)(deg + i0 + 4);
        v[0] = a.x; v[1] = a.y; v[2] = a.z; v[3] = a.w;
        v[4] = b.x; v[5] = b.y; v[6] = b.z; v[7] = b.w;
    } else {
        #pragma unroll
        for (int k = 0; k < 8; ++k) v[k] = (i0 + k < n) ? deg[i0 + k] : 0;
    }
    int tot = 0;
    #pragma unroll
    for (int k = 0; k < 8; ++k) tot += v[k];

    // wave-level inclusive scan of per-thread totals
    int x = tot;
    #pragma unroll
    for (int o = 1; o < 64; o <<= 1) {
        int y = __shfl_up(x, o);
        if (lane >= o) x += y;
    }
    __shared__ int wsum[4];
    if (lane == 63) wsum[wave] = x;
    __syncthreads();
    int wbase = 0;
    #pragma unroll
    for (int w = 0; w < 4; ++w) if (w < wave) wbase += wsum[w];

    int run = bbase[blockIdx.x] + wbase + (x - tot);  // exclusive prefix for item 0
    int o_[8];
    #pragma unroll
    for (int k = 0; k < 8; ++k) { o_[k] = run; run += v[k]; }

    if (fast) {
        int4 a = make_int4(o_[0], o_[1], o_[2], o_[3]);
        int4 b = make_int4(o_[4], o_[5], o_[6], o_[7]);
        *(int4*)(offs + i0) = a;     *(int4*)(offs + i0 + 4) = b;
        *(int4*)(cursor + i0) = a;   *(int4*)(cursor + i0 + 4) = b;
    } else {
        #pragma unroll
        for (int k = 0; k < 8; ++k)
            if (i0 + k < n) { offs[i0 + k] = o_[k]; cursor[i0 + k] = o_[k]; }
    }
}

__global__ void scatter_kernel(const int* __restrict__ rows,
                               const int* __restrict__ cols,
                               const float* __restrict__ vals,
                               int* __restrict__ cursor,
                               int2* __restrict__ csr,
                               int n_edges) {
    int e = blockIdx.x * blockDim.x + threadIdx.x;
    if (e >= n_edges) return;
    int r = rows[e];
    int pos = atomicAdd(&cursor[r], 1);
    int2 pk;
    pk.x = cols[e];
    pk.y = __float_as_int(vals[e]);
    csr[pos] = pk;
}

// ---------------- Layer 1: full SpMM (gather form) ----------------
__global__ void spmm_layer1(const int* __restrict__ offs,
                            const int2* __restrict__ csr,
                            const float* __restrict__ user_emb,
                            const float* __restrict__ item_emb,
                            float* __restrict__ emb1,
                            int n_nodes, int n_users) {
    int wave = (blockIdx.x * blockDim.x + threadIdx.x) >> 6;
    int lane = threadIdx.x & 63;
    if (wave >= n_nodes) return;
    int start = offs[wave];
    int end   = offs[wave + 1];
    float acc = 0.0f;
    for (int e = start; e < end; ++e) {
        int2 pk = csr[e];
        int c = pk.x;
        float v = __int_as_float(pk.y);
        const float* src = (c < n_users) ? (user_emb + (size_t)c * DIM)
                                         : (item_emb + (size_t)(c - n_users) * DIM);
        acc += v * src[lane];
    }
    emb1[(size_t)wave * DIM + lane] = acc;
}

// ---------------- Layer 2 (batch rows only) + epilogue ----------------
__global__ void epilogue_kernel(const int* __restrict__ users,
                                const int* __restrict__ items,
                                const float* __restrict__ user_emb,
                                const float* __restrict__ item_emb,
                                const float* __restrict__ emb1,
                                const int* __restrict__ offs,
                                const int2* __restrict__ csr,
                                float* __restrict__ out_u,
                                float* __restrict__ out_i,
                                float* __restrict__ out_s,
                                int batch, int n_users) {
    int wave = (blockIdx.x * blockDim.x + threadIdx.x) >> 6;
    int lane = threadIdx.x & 63;
    if (wave >= batch) return;
    int u  = users[wave];
    int it = items[wave];
    int ni = n_users + it;

    float ue2 = 0.0f;
    for (int e = offs[u]; e < offs[u + 1]; ++e) {
        int2 pk = csr[e];
        ue2 += __int_as_float(pk.y) * emb1[(size_t)pk.x * DIM + lane];
    }
    float ie2 = 0.0f;
    for (int e = offs[ni]; e < offs[ni + 1]; ++e) {
        int2 pk = csr[e];
        ie2 += __int_as_float(pk.y) * emb1[(size_t)pk.x * DIM + lane];
    }

    const float inv3 = 1.0f / 3.0f;
    float ue = (user_emb[(size_t)u * DIM + lane] + emb1[(size_t)u * DIM + lane] + ue2) * inv3;
    float ie = (item_emb[(size_t)it * DIM + lane] + emb1[(size_t)ni * DIM + lane] + ie2) * inv3;

    out_u[(size_t)wave * DIM + lane] = ue;
    out_i[(size_t)wave * DIM + lane] = ie;

    float s = ue * ie;
    #pragma unroll
    for (int o = 32; o > 0; o >>= 1) s += __shfl_down(s, o);
    if (lane == 0) out_s[wave] = s;
}

extern "C" void kernel_launch(void* const* d_in, const int* in_sizes, int n_in,
                              void* d_out, int out_size, void* d_ws, size_t ws_size,
                              hipStream_t stream) {
    const int*   users    = (const int*)d_in[0];
    const int*   items    = (const int*)d_in[1];
    const float* user_emb = (const float*)d_in[2];
    const float* item_emb = (const float*)d_in[3];
    const int*   rows     = (const int*)d_in[4];
    const int*   cols     = (const int*)d_in[5];
    const float* vals     = (const float*)d_in[6];

    const int batch   = in_sizes[0];
    const int n_users = in_sizes[2] / DIM;
    const int n_items = in_sizes[3] / DIM;
    const int n_nodes = n_users + n_items;
    const int n_edges = in_sizes[4];

    const int scan_blocks = (n_nodes + SCAN_ITEMS - 1) / SCAN_ITEMS;

    // Workspace layout
    char* p = (char*)d_ws;
    float* emb1   = (float*)p;  p += (size_t)n_nodes * DIM * sizeof(float);
    int*   deg    = (int*)p;    p += (size_t)n_nodes * sizeof(int);
    int*   offs   = (int*)p;    p += (size_t)(n_nodes + 1) * sizeof(int);
    int*   cursor = (int*)p;    p += (size_t)n_nodes * sizeof(int);
    int*   bsums  = (int*)p;    p += (size_t)scan_blocks * sizeof(int);
    int*   bbase  = (int*)p;    p += (size_t)scan_blocks * sizeof(int);
    // align to 8B for int2
    p = (char*)(((uintptr_t)p + 7) & ~(uintptr_t)7);
    int2*  csr    = (int2*)p;   p += (size_t)n_edges * sizeof(int2);

    float* out_u = (float*)d_out;
    float* out_i = out_u + (size_t)batch * DIM;
    float* out_s = out_i + (size_t)batch * DIM;

    // 1. CSR build
    hipMemsetAsync(deg, 0, (size_t)n_nodes * sizeof(int), stream);
    {
        int blocks = (n_edges + 255) / 256;
        hist_kernel<<<blocks, 256, 0, stream>>>(rows, deg, n_edges);
    }
    scan_blocksums<<<scan_blocks, 256, 0, stream>>>(deg, bsums, n_nodes);
    scan_bases<<<1, 256, 0, stream>>>(bsums, bbase, offs, n_nodes, scan_blocks);
    scan_final<<<scan_blocks, 256, 0, stream>>>(deg, bbase, offs, cursor, n_nodes);
    {
        int blocks = (n_edges + 255) / 256;
        scatter_kernel<<<blocks, 256, 0, stream>>>(rows, cols, vals, cursor,
                                                   csr, n_edges);
    }

    // 2. Layer 1 full SpMM: emb1 = A @ emb0
    {
        int waves_per_block = 4;  // 256 threads
        int blocks = (n_nodes + waves_per_block - 1) / waves_per_block;
        spmm_layer1<<<blocks, 256, 0, stream>>>(offs, csr,
                                                user_emb, item_emb, emb1,
                                                n_nodes, n_users);
    }

    // 3. Layer 2 (batch rows only) + outputs
    {
        int waves_per_block = 4;
        int blocks = (batch + waves_per_block - 1) / waves_per_block;
        epilogue_kernel<<<blocks, 256, 0, stream>>>(users, items,
                                                    user_emb, item_emb, emb1,
                                                    offs, csr,
                                                    out_u, out_i, out_s,
                                                    batch, n_users);
    }
}

// Round 3
// 1012.686 us; speedup vs baseline: 2.0816x; 1.3445x over previous
//
#include <hip/hip_runtime.h>
#include <hip/hip_bf16.h>

// LightGCN on MI355X.
// R1: multi-block scan; CSR packed as int2.
// R2->R3: 4x unroll + 4 accumulators in gather-SpMM loops (MLP: 4 gathers in
// flight per wave instead of 1; the loop was a serial load->fmac chain).

#define DIM 64
#define SCAN_ITEMS 2048   // elements per block in the scan (256 thr x 8)

// ---------------- CSR build ----------------

__global__ void hist_kernel(const int* __restrict__ rows, int* __restrict__ deg,
                            int n_edges) {
    int e = blockIdx.x * blockDim.x + threadIdx.x;
    if (e < n_edges) atomicAdd(&deg[rows[e]], 1);
}

// Pass 1: per-block sums of deg.
__global__ void scan_blocksums(const int* __restrict__ deg,
                               int* __restrict__ bsums, int n) {
    int base = blockIdx.x * SCAN_ITEMS;
    int s = 0;
    #pragma unroll
    for (int k = 0; k < 8; ++k) {
        int i = base + k * 256 + threadIdx.x;
        if (i < n) s += deg[i];
    }
    #pragma unroll
    for (int o = 32; o > 0; o >>= 1) s += __shfl_down(s, o);
    __shared__ int ws[4];
    int wave = threadIdx.x >> 6, lane = threadIdx.x & 63;
    if (lane == 0) ws[wave] = s;
    __syncthreads();
    if (threadIdx.x == 0) bsums[blockIdx.x] = ws[0] + ws[1] + ws[2] + ws[3];
}

// Pass 2: exclusive scan of block sums (nb small, single block, LDS-serial).
__global__ void scan_bases(const int* __restrict__ bsums, int* __restrict__ bbase,
                           int* __restrict__ offs, int n, int nb) {
    __shared__ int s[2048];
    int t = threadIdx.x;
    for (int i = t; i < nb; i += blockDim.x) s[i] = bsums[i];
    __syncthreads();
    if (t == 0) {
        int run = 0;
        for (int i = 0; i < nb; ++i) { int v = s[i]; s[i] = run; run += v; }
        offs[n] = run;   // total edge count
    }
    __syncthreads();
    for (int i = t; i < nb; i += blockDim.x) bbase[i] = s[i];
}

// Pass 3: per-block exclusive scan + base, writes offs and cursor.
__global__ void scan_final(const int* __restrict__ deg,
                           const int* __restrict__ bbase,
                           int* __restrict__ offs, int* __restrict__ cursor,
                           int n) {
    int base = blockIdx.x * SCAN_ITEMS;
    int t = threadIdx.x;
    int lane = t & 63, wave = t >> 6;
    int i0 = base + t * 8;

    int v[8];
    bool fast = (base + SCAN_ITEMS) <= n;
    if (fast) {
        int4 a = *(const int4*)(deg + i0);
        int4 b = *(const int4*)(deg + i0 + 4);
        v[0] = a.x; v[1] = a.y; v[2] = a.z; v[3] = a.w;
        v[4] = b.x; v[5] = b.y; v[6] = b.z; v[7] = b.w;
    } else {
        #pragma unroll
        for (int k = 0; k < 8; ++k) v[k] = (i0 + k < n) ? deg[i0 + k] : 0;
    }
    int tot = 0;
    #pragma unroll
    for (int k = 0; k < 8; ++k) tot += v[k];

    // wave-level inclusive scan of per-thread totals
    int x = tot;
    #pragma unroll
    for (int o = 1; o < 64; o <<= 1) {
        int y = __shfl_up(x, o);
        if (lane >= o) x += y;
    }
    __shared__ int wsum[4];
    if (lane == 63) wsum[wave] = x;
    __syncthreads();
    int wbase = 0;
    #pragma unroll
    for (int w = 0; w < 4; ++w) if (w < wave) wbase += wsum[w];

    int run = bbase[blockIdx.x] + wbase + (x - tot);  // exclusive prefix for item 0
    int o_[8];
    #pragma unroll
    for (int k = 0; k < 8; ++k) { o_[k] = run; run += v[k]; }

    if (fast) {
        int4 a = make_int4(o_[0], o_[1], o_[2], o_[3]);
        int4 b = make_int4(o_[4], o_[5], o_[6], o_[7]);
        *(int4*)(offs + i0) = a;     *(int4*)(offs + i0 + 4) = b;
        *(int4*)(cursor + i0) = a;   *(int4*)(cursor + i0 + 4) = b;
    } else {
        #pragma unroll
        for (int k = 0; k < 8; ++k)
            if (i0 + k < n) { offs[i0 + k] = o_[k]; cursor[i0 + k] = o_[k]; }
    }
}

__global__ void scatter_kernel(const int* __restrict__ rows,
                               const int* __restrict__ cols,
                               const float* __restrict__ vals,
                               int* __restrict__ cursor,
                               int2* __restrict__ csr,
                               int n_edges) {
    int e = blockIdx.x * blockDim.x + threadIdx.x;
    if (e >= n_edges) return;
    int r = rows[e];
    int pos = atomicAdd(&cursor[r], 1);
    int2 pk;
    pk.x = cols[e];
    pk.y = __float_as_int(vals[e]);
    csr[pos] = pk;
}

// ---------------- Layer 1: full SpMM (gather form) ----------------
// One wave per output row; lane l accumulates dim l. 4x unroll with 4
// accumulators so 4 csr loads + 4 row-gathers are in flight per wave.
__global__ void spmm_layer1(const int* __restrict__ offs,
                            const int2* __restrict__ csr,
                            const float* __restrict__ user_emb,
                            const float* __restrict__ item_emb,
                            float* __restrict__ emb1,
                            int n_nodes, int n_users) {
    int wave = (blockIdx.x * blockDim.x + threadIdx.x) >> 6;
    int lane = threadIdx.x & 63;
    if (wave >= n_nodes) return;
    int start = offs[wave];
    int end   = offs[wave + 1];

    float a0 = 0.0f, a1 = 0.0f, a2 = 0.0f, a3 = 0.0f;
    int e = start;
    for (; e + 4 <= end; e += 4) {
        int2 p0 = csr[e];
        int2 p1 = csr[e + 1];
        int2 p2 = csr[e + 2];
        int2 p3 = csr[e + 3];
        const float* s0 = (p0.x < n_users) ? (user_emb + (size_t)p0.x * DIM)
                                           : (item_emb + (size_t)(p0.x - n_users) * DIM);
        const float* s1 = (p1.x < n_users) ? (user_emb + (size_t)p1.x * DIM)
                                           : (item_emb + (size_t)(p1.x - n_users) * DIM);
        const float* s2 = (p2.x < n_users) ? (user_emb + (size_t)p2.x * DIM)
                                           : (item_emb + (size_t)(p2.x - n_users) * DIM);
        const float* s3 = (p3.x < n_users) ? (user_emb + (size_t)p3.x * DIM)
                                           : (item_emb + (size_t)(p3.x - n_users) * DIM);
        float g0 = s0[lane];
        float g1 = s1[lane];
        float g2 = s2[lane];
        float g3 = s3[lane];
        a0 += __int_as_float(p0.y) * g0;
        a1 += __int_as_float(p1.y) * g1;
        a2 += __int_as_float(p2.y) * g2;
        a3 += __int_as_float(p3.y) * g3;
    }
    for (; e < end; ++e) {
        int2 pk = csr[e];
        const float* src = (pk.x < n_users) ? (user_emb + (size_t)pk.x * DIM)
                                            : (item_emb + (size_t)(pk.x - n_users) * DIM);
        a0 += __int_as_float(pk.y) * src[lane];
    }
    emb1[(size_t)wave * DIM + lane] = (a0 + a1) + (a2 + a3);
}

// ---------------- Layer 2 (batch rows only) + epilogue ----------------
__device__ __forceinline__ float gather_row(const int* __restrict__ offs,
                                            const int2* __restrict__ csr,
                                            const float* __restrict__ emb1,
                                            int node, int lane) {
    int start = offs[node];
    int end   = offs[node + 1];
    float a0 = 0.0f, a1 = 0.0f, a2 = 0.0f, a3 = 0.0f;
    int e = start;
    for (; e + 4 <= end; e += 4) {
        int2 p0 = csr[e];
        int2 p1 = csr[e + 1];
        int2 p2 = csr[e + 2];
        int2 p3 = csr[e + 3];
        float g0 = emb1[(size_t)p0.x * DIM + lane];
        float g1 = emb1[(size_t)p1.x * DIM + lane];
        float g2 = emb1[(size_t)p2.x * DIM + lane];
        float g3 = emb1[(size_t)p3.x * DIM + lane];
        a0 += __int_as_float(p0.y) * g0;
        a1 += __int_as_float(p1.y) * g1;
        a2 += __int_as_float(p2.y) * g2;
        a3 += __int_as_float(p3.y) * g3;
    }
    for (; e < end; ++e) {
        int2 pk = csr[e];
        a0 += __int_as_float(pk.y) * emb1[(size_t)pk.x * DIM + lane];
    }
    return (a0 + a1) + (a2 + a3);
}

__global__ void epilogue_kernel(const int* __restrict__ users,
                                const int* __restrict__ items,
                                const float* __restrict__ user_emb,
                                const float* __restrict__ item_emb,
                                const float* __restrict__ emb1,
                                const int* __restrict__ offs,
                                const int2* __restrict__ csr,
                                float* __restrict__ out_u,
                                float* __restrict__ out_i,
                                float* __restrict__ out_s,
                                int batch, int n_users) {
    int wave = (blockIdx.x * blockDim.x + threadIdx.x) >> 6;
    int lane = threadIdx.x & 63;
    if (wave >= batch) return;
    int u  = users[wave];
    int it = items[wave];
    int ni = n_users + it;

    float ue2 = gather_row(offs, csr, emb1, u,  lane);
    float ie2 = gather_row(offs, csr, emb1, ni, lane);

    const float inv3 = 1.0f / 3.0f;
    float ue = (user_emb[(size_t)u * DIM + lane] + emb1[(size_t)u * DIM + lane] + ue2) * inv3;
    float ie = (item_emb[(size_t)it * DIM + lane] + emb1[(size_t)ni * DIM + lane] + ie2) * inv3;

    out_u[(size_t)wave * DIM + lane] = ue;
    out_i[(size_t)wave * DIM + lane] = ie;

    float s = ue * ie;
    #pragma unroll
    for (int o = 32; o > 0; o >>= 1) s += __shfl_down(s, o);
    if (lane == 0) out_s[wave] = s;
}

extern "C" void kernel_launch(void* const* d_in, const int* in_sizes, int n_in,
                              void* d_out, int out_size, void* d_ws, size_t ws_size,
                              hipStream_t stream) {
    const int*   users    = (const int*)d_in[0];
    const int*   items    = (const int*)d_in[1];
    const float* user_emb = (const float*)d_in[2];
    const float* item_emb = (const float*)d_in[3];
    const int*   rows     = (const int*)d_in[4];
    const int*   cols     = (const int*)d_in[5];
    const float* vals     = (const float*)d_in[6];

    const int batch   = in_sizes[0];
    const int n_users = in_sizes[2] / DIM;
    const int n_items = in_sizes[3] / DIM;
    const int n_nodes = n_users + n_items;
    const int n_edges = in_sizes[4];

    const int scan_blocks = (n_nodes + SCAN_ITEMS - 1) / SCAN_ITEMS;

    // Workspace layout
    char* p = (char*)d_ws;
    float* emb1   = (float*)p;  p += (size_t)n_nodes * DIM * sizeof(float);
    int*   deg    = (int*)p;    p += (size_t)n_nodes * sizeof(int);
    int*   offs   = (int*)p;    p += (size_t)(n_nodes + 1) * sizeof(int);
    int*   cursor = (int*)p;    p += (size_t)n_nodes * sizeof(int);
    int*   bsums  = (int*)p;    p += (size_t)scan_blocks * sizeof(int);
    int*   bbase  = (int*)p;    p += (size_t)scan_blocks * sizeof(int);
    // align to 8B for int2
    p = (char*)(((uintptr_t)p + 7) & ~(uintptr_t)7);
    int2*  csr    = (int2*)p;   p += (size_t)n_edges * sizeof(int2);

    float* out_u = (float*)d_out;
    float* out_i = out_u + (size_t)batch * DIM;
    float* out_s = out_i + (size_t)batch * DIM;

    // 1. CSR build
    hipMemsetAsync(deg, 0, (size_t)n_nodes * sizeof(int), stream);
    {
        int blocks = (n_edges + 255) / 256;
        hist_kernel<<<blocks, 256, 0, stream>>>(rows, deg, n_edges);
    }
    scan_blocksums<<<scan_blocks, 256, 0, stream>>>(deg, bsums, n_nodes);
    scan_bases<<<1, 256, 0, stream>>>(bsums, bbase, offs, n_nodes, scan_blocks);
    scan_final<<<scan_blocks, 256, 0, stream>>>(deg, bbase, offs, cursor, n_nodes);
    {
        int blocks = (n_edges + 255) / 256;
        scatter_kernel<<<blocks, 256, 0, stream>>>(rows, cols, vals, cursor,
                                                   csr, n_edges);
    }

    // 2. Layer 1 full SpMM: emb1 = A @ emb0
    {
        int waves_per_block = 4;  // 256 threads
        int blocks = (n_nodes + waves_per_block - 1) / waves_per_block;
        spmm_layer1<<<blocks, 256, 0, stream>>>(offs, csr,
                                                user_emb, item_emb, emb1,
                                                n_nodes, n_users);
    }

    // 3. Layer 2 (batch rows only) + outputs
    {
        int waves_per_block = 4;
        int blocks = (batch + waves_per_block - 1) / waves_per_block;
        epilogue_kernel<<<blocks, 256, 0, stream>>>(users, items,
                                                    user_emb, item_emb, emb1,
                                                    offs, csr,
                                                    out_u, out_i, out_s,
                                                    batch, n_users);
    }
}